// Round 1
// baseline (4449.120 us; speedup 1.0000x reference)
//
#include <hip/hip_runtime.h>
#include <math.h>

#define BB 4
#define TT 32
#define NN 1024
#define KK 16
#define HDIM 128
#define NO 512            // 4*HD gate rows
#define KG 132            // 4+HD contraction for G / layer-1 A

// d_out offsets (floats)
#define OUT1_SZ ((size_t)BB*TT*132*NN)          // 17,301,504
#define OH (OUT1_SZ)                             // h region
#define OC (OH + (size_t)BB*HDIM*NN)             // c region
#define OG (OC + (size_t)BB*HDIM*NN)             // group_ind region

// ---------------------------------------------------------------------------
// Weight prep: build transposed effective weights.
//   Layer0: gates = Wa0@pos_t + Wg0@[pp;h0] + b0,  Wa0 = w0[:,0:4]-w0[:,4:8]
//           Wg0 = w0[:,4:136]
//   Layer1: gates = Wa1@[pos_t;h0_t] + Wg1@[pp;h1] + b1
//           Wa1 cols<4 = w1[:,c]-w1[:,132+c], cols>=4 = w1[:,c]; Wg1 = w1[:,132:264]
// All stored transposed [k][512] for coalesced GEMM staging.
// ---------------------------------------------------------------------------
__global__ __launch_bounds__(256) void prep_weights(
    const float* __restrict__ w0, const float* __restrict__ w1,
    float* __restrict__ WaT0, float* __restrict__ WgT0,
    float* __restrict__ WaT1, float* __restrict__ WgT1)
{
  int idx = blockIdx.x * 256 + threadIdx.x;
  if (idx >= KG * NO) return;
  int k = idx / NO, o = idx - k * NO;
  WgT0[idx] = w0[o * 136 + 4 + k];
  WgT1[idx] = w1[o * 264 + 132 + k];
  float a1 = w1[o * 264 + k];
  if (k < 4) a1 -= w1[o * 264 + 132 + k];
  WaT1[idx] = a1;
  if (k < 4) WaT0[k * NO + o] = w0[o * 136 + k] - w0[o * 136 + 4 + k];
}

// ---------------------------------------------------------------------------
// KNN: per (b,t): for each query point n in frame t, exact 16 nearest in frame
// max(t-1,0) by d2 = q2 + r2 - 2*qr (pinned rounding to mimic reference).
// One thread per row; sorted insertion (ties -> lower index first, matching
// lax.top_k). Writes int indices to ws and float copies to d_out.
// ---------------------------------------------------------------------------
__global__ __launch_bounds__(512) void knn_kernel(
    const float* __restrict__ x, int* __restrict__ gind, float* __restrict__ gfloat)
{
  __shared__ float rx[NN], ry[NN], rz[NN], rr[NN];
  int b = blockIdx.z, t = blockIdx.y;
  int tp = (t == 0) ? 0 : t - 1;
  const float* xr = x + (size_t)(b * TT + tp) * 4 * NN;
  for (int m = threadIdx.x; m < NN; m += 512) {
    float a = xr[m], e = xr[NN + m], c = xr[2 * NN + m];
    rx[m] = a; ry[m] = e; rz[m] = c;
    rr[m] = __fadd_rn(__fadd_rn(__fmul_rn(a, a), __fmul_rn(e, e)), __fmul_rn(c, c));
  }
  __syncthreads();
  int n = blockIdx.x * 512 + threadIdx.x;
  const float* xq = x + (size_t)(b * TT + t) * 4 * NN;
  float qx = xq[n], qy = xq[NN + n], qz = xq[2 * NN + n];
  float q2 = __fadd_rn(__fadd_rn(__fmul_rn(qx, qx), __fmul_rn(qy, qy)), __fmul_rn(qz, qz));
  float bd[KK]; int bi[KK];
#pragma unroll
  for (int i = 0; i < KK; ++i) { bd[i] = 3.402823466e38f; bi[i] = 0; }
  for (int m = 0; m < NN; ++m) {
    float s = __fmaf_rn(qz, rz[m], __fmaf_rn(qy, ry[m], __fmaf_rn(qx, rx[m], 0.0f)));
    float d2 = __fsub_rn(__fadd_rn(q2, rr[m]), __fmul_rn(2.0f, s));
    if (d2 < bd[KK - 1]) {
      // exactly one slot gets d2: the i with bd[i-1] <= d2 < bd[i] (or slot 0)
#pragma unroll
      for (int i = KK - 1; i > 0; --i) {
        float pv = bd[i - 1]; int pi = bi[i - 1];
        if (pv > d2)            { bd[i] = pv; bi[i] = pi; }
        else if (bd[i] > d2)    { bd[i] = d2; bi[i] = m; }
      }
      if (bd[0] > d2) { bd[0] = d2; bi[0] = m; }
    }
  }
  size_t base = ((size_t)(b * TT + t) * NN + n) * KK;
#pragma unroll
  for (int i = 0; i < KK; ++i) { gind[base + i] = bi[i]; gfloat[base + i] = (float)bi[i]; }
}

// ---------------------------------------------------------------------------
// Fused GEMM: per (b): A[n][512] and G[n][512] (transposed layouts).
//   G = WgT^T @ [pp_t(4); h_g(128)]       (K=132)
//   A = WaT^T @ Xa + bias                 (KA=4: Xa=pos_t; KA=132: [pos_t; h_a])
// 64o x 64n tiles, K-chunks of 44, LDS-staged operands.
// ---------------------------------------------------------------------------
template<int KA>
__global__ __launch_bounds__(256) void gemm_ag(
    const float* __restrict__ WgT, const float* __restrict__ WaT,
    const float* __restrict__ bias,
    const float* __restrict__ x,
    const float* __restrict__ h_g, const float* __restrict__ h_a,
    int t, int tp,
    float* __restrict__ Aout, float* __restrict__ Gout)
{
  __shared__ float sXg[44][68];
  __shared__ float sWg[44][64];
  __shared__ float sXa[(KA == 4) ? 4 : 44][68];
  __shared__ float sWa[(KA == 4) ? 4 : 44][64];

  int tid = threadIdx.x;
  int nb = blockIdx.x * 64, ob = blockIdx.y * 64, b = blockIdx.z;
  int ty = tid >> 4, tx = tid & 15;
  int o0 = ty * 4, n0 = tx * 4;

  float accG[4][4] = {};
  float accA[4][4];
#pragma unroll
  for (int i = 0; i < 4; ++i) {
    float bv = bias[ob + o0 + i];
#pragma unroll
    for (int j = 0; j < 4; ++j) accA[i][j] = bv;
  }

  const float* xp_prev = x + (size_t)(b * TT + tp) * 4 * NN;  // pp rows (frame t-1)
  const float* xp_cur  = x + (size_t)(b * TT + t) * 4 * NN;   // pos_t rows

#pragma unroll
  for (int ic = 0; ic < 3; ++ic) {
    const int kc0 = ic * 44;
    // stage W tiles (rows k, coalesced along o)
    for (int i2 = tid; i2 < 44 * 64; i2 += 256) {
      int k = i2 >> 6, o = i2 & 63;
      sWg[k][o] = WgT[(size_t)(kc0 + k) * NO + ob + o];
      if (KA == 132) sWa[k][o] = WaT[(size_t)(kc0 + k) * NO + ob + o];
    }
    if (KA == 4 && ic == 0 && tid < 4 * 64) {
      int k = tid >> 6, o = tid & 63;
      sWa[k][o] = WaT[k * NO + ob + o];
    }
    // stage X position rows (chunk 0 only): rows 0..3
    if (ic == 0) {
      int k = tid >> 6, n = tid & 63;
      sXg[k][n] = xp_prev[k * NN + nb + n];
      sXa[k][n] = xp_cur[k * NN + nb + n];
    }
    // stage X h-rows (coalesced along j, transposed into LDS)
    {
      const int j0 = (ic == 0) ? 0 : (kc0 - 4);
      const int jc = (ic == 0) ? 40 : 44;
      for (int i2 = tid; i2 < 64 * jc; i2 += 256) {
        int n = i2 / jc, jj = i2 - n * jc;
        int krow = j0 + jj + 4 - kc0;
        sXg[krow][n] = h_g[((size_t)b * NN + nb + n) * HDIM + j0 + jj];
        if (KA == 132)
          sXa[krow][n] = h_a[((size_t)b * NN + nb + n) * HDIM + j0 + jj];
      }
    }
    __syncthreads();

    if (KA == 4 && ic == 0) {
#pragma unroll
      for (int k = 0; k < 4; ++k) {
        float4 wa = *(const float4*)&sWa[k][o0];
        float4 xa = *(const float4*)&sXa[k][n0];
        float wv[4] = {wa.x, wa.y, wa.z, wa.w};
        float xv[4] = {xa.x, xa.y, xa.z, xa.w};
#pragma unroll
        for (int i = 0; i < 4; ++i)
#pragma unroll
          for (int j = 0; j < 4; ++j) accA[i][j] = fmaf(wv[i], xv[j], accA[i][j]);
      }
    }
#pragma unroll 4
    for (int k = 0; k < 44; ++k) {
      float4 wg = *(const float4*)&sWg[k][o0];
      float4 xg = *(const float4*)&sXg[k][n0];
      float wv[4] = {wg.x, wg.y, wg.z, wg.w};
      float xv[4] = {xg.x, xg.y, xg.z, xg.w};
#pragma unroll
      for (int i = 0; i < 4; ++i)
#pragma unroll
        for (int j = 0; j < 4; ++j) accG[i][j] = fmaf(wv[i], xv[j], accG[i][j]);
      if (KA == 132) {
        float4 wa = *(const float4*)&sWa[k][o0];
        float4 xa = *(const float4*)&sXa[k][n0];
        float wv2[4] = {wa.x, wa.y, wa.z, wa.w};
        float xv2[4] = {xa.x, xa.y, xa.z, xa.w};
#pragma unroll
        for (int i = 0; i < 4; ++i)
#pragma unroll
          for (int j = 0; j < 4; ++j) accA[i][j] = fmaf(wv2[i], xv2[j], accA[i][j]);
      }
    }
    __syncthreads();
  }
#pragma unroll
  for (int j = 0; j < 4; ++j) {
    size_t row = ((size_t)b * NN + nb + n0 + j) * NO + ob + o0;
    *(float4*)&Gout[row] = make_float4(accG[0][j], accG[1][j], accG[2][j], accG[3][j]);
    *(float4*)&Aout[row] = make_float4(accA[0][j], accA[1][j], accA[2][j], accA[3][j]);
  }
}

// ---------------------------------------------------------------------------
// Elementwise LSTM step: per (b,n,j) gather gates at the 16 neighbors,
// activations, max over k. c is ping-ponged (gather-old / write-new).
// gates split: ci rows 0:128, cf 128:256, co 256:384, cg 384:512.
// ---------------------------------------------------------------------------
__global__ __launch_bounds__(256) void ew_step(
    const float* __restrict__ A, const float* __restrict__ G,
    const int* __restrict__ gind,
    const float* __restrict__ c_in, float* __restrict__ c_out,
    float* __restrict__ h_out, int t)
{
  int tid = threadIdx.x;
  int j = tid & 127, ns = tid >> 7;
  int b = blockIdx.y;
  int n = blockIdx.x * 2 + ns;
  const float* Ap = A + ((size_t)b * NN + n) * NO;
  float a0 = Ap[j], a1 = Ap[128 + j], a2 = Ap[256 + j], a3 = Ap[384 + j];
  const int* ip = gind + ((size_t)(b * TT + t) * NN + n) * KK;
  const float* Gb = G + (size_t)b * NN * NO;
  const float* cb = c_in + (size_t)b * NN * HDIM;
  float hmax = -3.402823466e38f, cmax = -3.402823466e38f;
#pragma unroll 4
  for (int k = 0; k < KK; ++k) {
    int m = ip[k];
    const float* Gp = Gb + (size_t)m * NO;
    float gi = a0 + Gp[j];
    float gf = a1 + Gp[128 + j];
    float go = a2 + Gp[256 + j];
    float gg = a3 + Gp[384 + j];
    float cg = cb[(size_t)m * HDIM + j];
    float si = 1.0f / (1.0f + __expf(-gi));
    float sf = 1.0f / (1.0f + __expf(-gf));
    float so = 1.0f / (1.0f + __expf(-go));
    float tg = 1.0f - 2.0f / (1.0f + __expf(2.0f * gg));
    float cn = sf * cg + si * tg;
    float tc = 1.0f - 2.0f / (1.0f + __expf(2.0f * cn));
    float hn = so * tc;
    hmax = fmaxf(hmax, hn);
    cmax = fmaxf(cmax, cn);
  }
  h_out[((size_t)b * NN + n) * HDIM + j] = hmax;
  c_out[((size_t)b * NN + n) * HDIM + j] = cmax;
}

// ---------------------------------------------------------------------------
// Transpose (b,n,j)[N][128] -> dst[dstBase + b*bStride + j*N + n]
// ---------------------------------------------------------------------------
__global__ __launch_bounds__(256) void transpose_nj_jn(
    const float* __restrict__ src, float* __restrict__ dst,
    size_t dstBase, size_t bStride)
{
  __shared__ float tl[64][65];
  int tid = threadIdx.x;
  int n0 = blockIdx.x * 64, j0 = blockIdx.y * 64, b = blockIdx.z;
  int c = tid & 63, r4 = tid >> 6;
#pragma unroll
  for (int i = 0; i < 16; ++i) {
    int r = r4 + i * 4;
    tl[r][c] = src[((size_t)b * NN + n0 + r) * HDIM + j0 + c];
  }
  __syncthreads();
  float* dp = dst + dstBase + (size_t)b * bStride;
#pragma unroll
  for (int i = 0; i < 16; ++i) {
    int rr = r4 + i * 4;
    dp[(size_t)(j0 + rr) * NN + n0 + c] = tl[c][rr];
  }
}

// out1 position channels: out1[b][t][0:4][n] = x[b][t][0:4][n]
__global__ __launch_bounds__(256) void pos_copy(const float* __restrict__ x,
                                                float* __restrict__ out)
{
  int i = blockIdx.x * 256 + threadIdx.x;
  if (i >= BB * TT * 4 * NN) return;
  int n = i & (NN - 1);
  int btc = i >> 10;
  int c = btc & 3, bt = btc >> 2;
  out[((size_t)bt * 132 + c) * NN + n] = x[i];
}

extern "C" void kernel_launch(void* const* d_in, const int* in_sizes, int n_in,
                              void* d_out, int out_size, void* d_ws, size_t ws_size,
                              hipStream_t stream)
{
  const float* x  = (const float*)d_in[0];
  const float* w0 = (const float*)d_in[1];
  const float* b0 = (const float*)d_in[2];
  const float* w1 = (const float*)d_in[3];
  const float* b1 = (const float*)d_in[4];
  float* out = (float*)d_out;

  float* wsf = (float*)d_ws;
  int*   gind = (int*)d_ws;
  size_t off = (size_t)BB * TT * NN * KK;          // gind ints
  const size_t HSZ = (size_t)BB * NN * HDIM;       // 524288
  float* h0  = wsf + off; off += HSZ;
  float* h1  = wsf + off; off += HSZ;
  float* c0a = wsf + off; off += HSZ;
  float* c0b = wsf + off; off += HSZ;
  float* c1a = wsf + off; off += HSZ;
  float* c1b = wsf + off; off += HSZ;
  float* Abuf = wsf + off; off += (size_t)BB * NN * NO;
  float* Gbuf = wsf + off; off += (size_t)BB * NN * NO;
  float* WaT0 = wsf + off; off += 4 * NO;
  float* WgT0 = wsf + off; off += (size_t)KG * NO;
  float* WaT1 = wsf + off; off += (size_t)KG * NO;
  float* WgT1 = wsf + off; off += (size_t)KG * NO;

  hipMemsetAsync(h0, 0, HSZ * 4, stream);
  hipMemsetAsync(h1, 0, HSZ * 4, stream);
  hipMemsetAsync(c0a, 0, HSZ * 4, stream);
  hipMemsetAsync(c1a, 0, HSZ * 4, stream);

  prep_weights<<<(KG * NO + 255) / 256, 256, 0, stream>>>(w0, w1, WaT0, WgT0, WaT1, WgT1);
  knn_kernel<<<dim3(2, TT, BB), 512, 0, stream>>>(x, gind, out + OG);
  pos_copy<<<(BB * TT * 4 * NN + 255) / 256, 256, 0, stream>>>(x, out);

  float* c0[2] = {c0a, c0b};
  float* c1[2] = {c1a, c1b};
  for (int t = 0; t < TT; ++t) {
    int tp = t ? t - 1 : 0;
    // layer 0
    gemm_ag<4><<<dim3(16, 8, BB), 256, 0, stream>>>(
        WgT0, WaT0, b0, x, h0, (const float*)nullptr, t, tp, Abuf, Gbuf);
    ew_step<<<dim3(NN / 2, BB), 256, 0, stream>>>(
        Abuf, Gbuf, gind, c0[t & 1], c0[(t & 1) ^ 1], h0, t);
    // layer 1 (h0 now holds hs0_t)
    gemm_ag<132><<<dim3(16, 8, BB), 256, 0, stream>>>(
        WgT1, WaT1, b1, x, h1, h0, t, tp, Abuf, Gbuf);
    ew_step<<<dim3(NN / 2, BB), 256, 0, stream>>>(
        Abuf, Gbuf, gind, c1[t & 1], c1[(t & 1) ^ 1], h1, t);
    // out1[b][t][4:132][n] = h1^T
    transpose_nj_jn<<<dim3(16, 2, BB), 256, 0, stream>>>(
        h1, out, (size_t)t * 132 * NN + 4 * NN, (size_t)TT * 132 * NN);
  }
  // final h, c outputs (layer 1 state after t=T-1; c lands in buffer index 0)
  transpose_nj_jn<<<dim3(16, 2, BB), 256, 0, stream>>>(h1, out, OH, (size_t)HDIM * NN);
  transpose_nj_jn<<<dim3(16, 2, BB), 256, 0, stream>>>(c1[0], out, OC, (size_t)HDIM * NN);
}